// Round 1
// baseline (1006.495 us; speedup 1.0000x reference)
//
#include <hip/hip_runtime.h>

// ---------------------------------------------------------------------------
// Decoder step: attention (enc@W1^T fused tanh/softmax/ctx) + GRU + fc head.
// Strategy: bf16 MFMA everywhere matmul-shaped; enc read from HBM exactly once
// (kept resident in LDS per block, XOR-swizzled); small GEMMs via a generic
// 128x128-tile bf16 kernel with padded K/N so there is no edge handling.
// R0 changes vs previous session: (1) attention logits reduction is now fully
// deterministic (per-wave LDS slabs + fixed-order sum, no float atomics) to
// satisfy the replay-reproducibility tripwire; (2) all prep/convert/embed
// launches fused into one kernel (fewer graph nodes).
// ---------------------------------------------------------------------------

typedef __attribute__((ext_vector_type(4))) float floatx4;
typedef __attribute__((ext_vector_type(8))) short short8;

#define DEV static __device__ __forceinline__

DEV unsigned short f2bf(float f) {          // fp32 -> bf16, round-nearest-even
  unsigned u = __float_as_uint(f);
  u = u + 0x7fffu + ((u >> 16) & 1u);
  return (unsigned short)(u >> 16);
}
DEV float bf2f(unsigned short s) { return __uint_as_float(((unsigned)s) << 16); }
DEV float tanh_fast(float x) {              // saturates correctly at +-inf
  float e = __expf(2.f * x);
  return 1.f - 2.f / (e + 1.f);
}
DEV float sigmoid_fast(float x) { return 1.f / (1.f + __expf(-x)); }

// ---------------------------------------------------------------------------
// Fused prep: all fp32->bf16 padded converts + bias folds + embedding gather
// in ONE launch. Segments dispatched by blockIdx ranges (all constants are
// compile-time literals so the div/mod lower to magic multiplies).
// ---------------------------------------------------------------------------
DEV void convpad_body(const float* __restrict__ src,
                      unsigned short* __restrict__ dst,
                      int idx, int Nsrc, int Kin, int Kp) {
  int n = idx / Kp, k = idx - n * Kp;
  float v = (k < Kin && n < Nsrc) ? src[(size_t)n * Kin + k] : 0.f;
  dst[idx] = f2bf(v);
}

// block counts per segment (256 threads each)
#define PB_W1 1024
#define PB_W2 1024
#define PB_WIH 4992
#define PB_WHH 3072
#define PB_FC1 768
#define PB_FC2 192
#define PB_HID 4096
#define PB_EMB 2560
#define PB_BIAS 2
#define PREP_BLOCKS (PB_W1 + PB_W2 + PB_WIH + PB_WHH + PB_FC1 + PB_FC2 + PB_HID + PB_EMB + PB_BIAS)

__global__ void prep_all(
    const float* __restrict__ W1w, unsigned short* __restrict__ W1bf,
    const float* __restrict__ W2w, unsigned short* __restrict__ W2bf,
    const float* __restrict__ wih, unsigned short* __restrict__ wihbf,
    const float* __restrict__ whh, unsigned short* __restrict__ whhbf,
    const float* __restrict__ fc1w, unsigned short* __restrict__ fc1wbf,
    const float* __restrict__ fc2w, unsigned short* __restrict__ fc2wbf,
    const float* __restrict__ hidden, unsigned short* __restrict__ hidbf,
    const int* __restrict__ x, const float* __restrict__ embt,
    unsigned short* __restrict__ gin,
    const float* __restrict__ W1b, const float* __restrict__ W2b,
    float* __restrict__ keyb,
    const float* __restrict__ fc1b, float* __restrict__ fc1bp) {
  int bid = blockIdx.x;
  int tid = threadIdx.x;
  if (bid < PB_W1) {
    convpad_body(W1w, W1bf, bid * 256 + tid, 512, 512, 512);
    return;
  }
  bid -= PB_W1;
  if (bid < PB_W2) {
    convpad_body(W2w, W2bf, bid * 256 + tid, 512, 512, 512);
    return;
  }
  bid -= PB_W2;
  if (bid < PB_WIH) {
    convpad_body(wih, wihbf, bid * 256 + tid, 1536, 812, 832);
    return;
  }
  bid -= PB_WIH;
  if (bid < PB_WHH) {
    convpad_body(whh, whhbf, bid * 256 + tid, 1536, 512, 512);
    return;
  }
  bid -= PB_WHH;
  if (bid < PB_FC1) {
    convpad_body(fc1w, fc1wbf, bid * 256 + tid, 300, 512, 512);
    return;
  }
  bid -= PB_FC1;
  if (bid < PB_FC2) {
    convpad_body(fc2w, fc2wbf, bid * 256 + tid, 128, 300, 384);
    return;
  }
  bid -= PB_FC2;
  if (bid < PB_HID) {
    convpad_body(hidden, hidbf, bid * 256 + tid, 2048, 512, 512);
    return;
  }
  bid -= PB_HID;
  if (bid < PB_EMB) {
    int idx = bid * 256 + tid;            // 2048 * 320
    int b = idx / 320, e = idx - b * 320;
    float v = (e < 300) ? embt[(size_t)x[b] * 300 + e] : 0.f;
    gin[(size_t)b * 832 + 512 + e] = f2bf(v);
    return;
  }
  bid -= PB_EMB;
  {
    int i = bid * 256 + tid;
    if (i < 512) keyb[i] = W1b[i] + W2b[i];   // W1_b + W2_b folded into key
    if (i < 384) fc1bp[i] = (i < 300) ? fc1b[i] : 0.f;
  }
}

// ---------------------------------------------------------------------------
// Generic bf16 GEMM: C[M,N] = A[M,K] @ B[N,K]^T + bias[n], M=2048 here,
// N,K multiples of 128/64. 256 threads, block tile 128x128, wave tile 64x64.
// LDS granule-XOR swizzle keeps ds_read_b128 at 2-way conflicts (free).
// EPI 0: f32 store.  EPI 1: leaky_relu(0.01) -> bf16 store.
// ---------------------------------------------------------------------------
template <int EPI>
__global__ __launch_bounds__(256, 3) void gemm_bt(
    const unsigned short* __restrict__ A, int lda,
    const unsigned short* __restrict__ Bm, int ldb,
    const float* __restrict__ bias,
    void* __restrict__ Cp, int ldc, int K) {
  __shared__ unsigned short As[128 * 64];
  __shared__ unsigned short Bs[128 * 64];
  int tid = threadIdx.x;
  int bm = blockIdx.x * 128, bn = blockIdx.y * 128;
  int lane = tid & 63, wave = tid >> 6;
  int l15 = lane & 15, l4 = lane >> 4;
  int wm = (wave >> 1) * 64, wn = (wave & 1) * 64;

  floatx4 zero = {0.f, 0.f, 0.f, 0.f};
  floatx4 acc[4][4];
#pragma unroll
  for (int i = 0; i < 4; ++i)
#pragma unroll
    for (int j = 0; j < 4; ++j) acc[i][j] = zero;

  int row = tid >> 1;                 // staging: thread -> (row, 4 granules)
  int gc0 = (tid & 1) * 4;
  const unsigned short* Aptr = A + (size_t)(bm + row) * lda + gc0 * 8;
  const unsigned short* Bptr = Bm + (size_t)(bn + row) * ldb + gc0 * 8;
  int rslot7 = row & 7, lslot7 = l15 & 7;

  int nk = K >> 6;
  for (int kt = 0; kt < nk; ++kt) {
#pragma unroll
    for (int i = 0; i < 4; ++i) {
      int slot = (gc0 + i) ^ rslot7;
      *(uint4*)&As[row * 64 + slot * 8] = *(const uint4*)(Aptr + kt * 64 + i * 8);
      *(uint4*)&Bs[row * 64 + slot * 8] = *(const uint4*)(Bptr + kt * 64 + i * 8);
    }
    __syncthreads();
#pragma unroll
    for (int ks = 0; ks < 2; ++ks) {
      int slot = (ks * 4 + l4) ^ lslot7;
      short8 av[4], bv[4];
#pragma unroll
      for (int mt = 0; mt < 4; ++mt)
        av[mt] = *(const short8*)&As[(wm + mt * 16 + l15) * 64 + slot * 8];
#pragma unroll
      for (int nt = 0; nt < 4; ++nt)
        bv[nt] = *(const short8*)&Bs[(wn + nt * 16 + l15) * 64 + slot * 8];
#pragma unroll
      for (int mt = 0; mt < 4; ++mt)
#pragma unroll
        for (int nt = 0; nt < 4; ++nt)
          acc[mt][nt] = __builtin_amdgcn_mfma_f32_16x16x32_bf16(
              av[mt], bv[nt], acc[mt][nt], 0, 0, 0);
    }
    __syncthreads();
  }

#pragma unroll
  for (int nt = 0; nt < 4; ++nt) {
    int n = bn + wn + nt * 16 + l15;
    float bvv = bias[n];
#pragma unroll
    for (int mt = 0; mt < 4; ++mt) {
#pragma unroll
      for (int r = 0; r < 4; ++r) {
        int m = bm + wm + mt * 16 + l4 * 4 + r;
        float v = acc[mt][nt][r] + bvv;
        if (EPI == 1) {
          v = v > 0.f ? v : 0.01f * v;
          ((unsigned short*)Cp)[(size_t)m * ldc + n] = f2bf(v);
        } else {
          ((float*)Cp)[(size_t)m * ldc + n] = v;
        }
      }
    }
  }
}

// ---------------------------------------------------------------------------
// Fused attention: per batch row b (one block, 512 threads = 8 waves):
//  phase0: enc[b] (128x512 f32) -> LDS bf16, XOR-swizzled 16B granules
//  GEMM:   score_pre = enc[b] @ W1^T, barrier-free K-loop (A in LDS resident,
//          B frags straight from L2-resident W1-bf16), wave w owns 64 cols
//  epi:    tanh(score_pre + key) dot V_w -> per-wave partial logits into a
//          private LDS slab (DETERMINISTIC: no atomics), wave 0 sums in fixed
//          order, softmax over S=128, then ctx[h] = sum_s attw[s]*enc_lds[s][h]
//  writes ctx as bf16 into gin[:, 0:512]
// ---------------------------------------------------------------------------
#define ATTN_LDS_BYTES (128 * 512 * 2 + 8 * 128 * 4 + 128 * 4)

__global__ __launch_bounds__(512, 2) void attn_kernel(
    const float* __restrict__ enc, const unsigned short* __restrict__ W1b16,
    const float* __restrict__ key, const float* __restrict__ Vw,
    unsigned short* __restrict__ gin) {
  extern __shared__ unsigned char smem_raw[];
  unsigned short* Albs = (unsigned short*)smem_raw;            // 128KB
  float* lds_part = (float*)(smem_raw + 128 * 512 * 2);        // [8][128]
  float* lds_attw = lds_part + 8 * 128;                        // 128 f32

  int b = blockIdx.x;
  int tid = threadIdx.x;
  const float* encb = enc + (size_t)b * 128 * 512;

  // ---- phase 0: stage enc[b] as swizzled bf16 granules (8 elems = 16B) ----
#pragma unroll 2
  for (int it = 0; it < 16; ++it) {
    int g = it * 512 + tid;          // granule id 0..8191
    int m = g >> 6, gc = g & 63;
    const float4* src = (const float4*)(encb + (size_t)g * 8);
    float4 lo = src[0], hi = src[1];
    uint4 pk;
    pk.x = (unsigned)f2bf(lo.x) | ((unsigned)f2bf(lo.y) << 16);
    pk.y = (unsigned)f2bf(lo.z) | ((unsigned)f2bf(lo.w) << 16);
    pk.z = (unsigned)f2bf(hi.x) | ((unsigned)f2bf(hi.y) << 16);
    pk.w = (unsigned)f2bf(hi.z) | ((unsigned)f2bf(hi.w) << 16);
    int slot = gc ^ (m & 7);
    *(uint4*)&Albs[m * 512 + slot * 8] = pk;
  }
  __syncthreads();

  // ---- GEMM phase: barrier-free ----
  int wave = tid >> 6, lane = tid & 63;
  int l15 = lane & 15, l4 = lane >> 4, lslot7 = l15 & 7;
  int n0 = wave * 64;

  floatx4 zero = {0.f, 0.f, 0.f, 0.f};
  floatx4 acc[8][4];
#pragma unroll
  for (int i = 0; i < 8; ++i)
#pragma unroll
    for (int j = 0; j < 4; ++j) acc[i][j] = zero;

#pragma unroll 2
  for (int kt = 0; kt < 16; ++kt) {
    int slot = (kt * 4 + l4) ^ lslot7;
    short8 av[8], bv[4];
#pragma unroll
    for (int nt = 0; nt < 4; ++nt) {   // B frags from global (L2-hot W1 bf16)
      int n = n0 + nt * 16 + l15;
      bv[nt] = *(const short8*)(W1b16 + (size_t)n * 512 + kt * 32 + l4 * 8);
    }
#pragma unroll
    for (int mt = 0; mt < 8; ++mt)
      av[mt] = *(const short8*)&Albs[(mt * 16 + l15) * 512 + slot * 8];
#pragma unroll
    for (int mt = 0; mt < 8; ++mt)
#pragma unroll
      for (int nt = 0; nt < 4; ++nt)
        acc[mt][nt] = __builtin_amdgcn_mfma_f32_16x16x32_bf16(
            av[mt], bv[nt], acc[mt][nt], 0, 0, 0);
  }

  // ---- epilogue: per-wave partial logits (deterministic, no atomics) ----
  float kb[4], vwl[4];
#pragma unroll
  for (int nt = 0; nt < 4; ++nt) {
    int col = n0 + nt * 16 + l15;
    kb[nt] = key[(size_t)b * 512 + col];
    vwl[nt] = Vw[col];
  }
#pragma unroll
  for (int mt = 0; mt < 8; ++mt) {
#pragma unroll
    for (int r = 0; r < 4; ++r) {
      float c = 0.f;
#pragma unroll
      for (int nt = 0; nt < 4; ++nt)
        c += tanh_fast(acc[mt][nt][r] + kb[nt]) * vwl[nt];
      c += __shfl_xor(c, 1, 64);
      c += __shfl_xor(c, 2, 64);
      c += __shfl_xor(c, 4, 64);
      c += __shfl_xor(c, 8, 64);
      if (l15 == 0) lds_part[wave * 128 + mt * 16 + l4 * 4 + r] = c;
    }
  }
  __syncthreads();

  // ---- softmax over S=128 (wave 0; V_b dropped: shift-invariant) ----
  if (wave == 0) {
    float l0 = 0.f, l1 = 0.f;
#pragma unroll
    for (int w = 0; w < 8; ++w) {      // fixed-order sum: deterministic
      l0 += lds_part[w * 128 + lane];
      l1 += lds_part[w * 128 + lane + 64];
    }
    float mx = fmaxf(l0, l1);
#pragma unroll
    for (int o = 32; o >= 1; o >>= 1) mx = fmaxf(mx, __shfl_xor(mx, o, 64));
    float e0 = __expf(l0 - mx), e1 = __expf(l1 - mx);
    float s = e0 + e1;
#pragma unroll
    for (int o = 32; o >= 1; o >>= 1) s += __shfl_xor(s, o, 64);
    float inv = 1.f / s;
    lds_attw[lane] = e0 * inv;
    lds_attw[lane + 64] = e1 * inv;
  }
  __syncthreads();

  // ---- ctx[h] = sum_s attw[s] * enc_lds[s][h], h = tid ----
  int h = tid, gc = h >> 3, off = h & 7;
  float cx = 0.f;
  for (int s = 0; s < 128; ++s)
    cx += lds_attw[s] * bf2f(Albs[s * 512 + ((gc ^ (s & 7)) << 3) + off]);
  gin[(size_t)b * 832 + h] = f2bf(cx);
}

// ---------------------------------------------------------------------------
// GRU elementwise: gates from gi/gh (f32), h0 in f32; writes h_new (f32 to
// d_out) and bf16 copy for the fc1 GEMM.
// ---------------------------------------------------------------------------
__global__ void gru_kernel(const float* __restrict__ gi,
                           const float* __restrict__ gh,
                           const float* __restrict__ hidden,
                           float* __restrict__ outh,
                           unsigned short* __restrict__ hnewbf) {
  int idx = blockIdx.x * 256 + threadIdx.x;   // 2048*512
  int b = idx >> 9, h = idx & 511;
  const float* gib = gi + (size_t)b * 1536;
  const float* ghb = gh + (size_t)b * 1536;
  float r = sigmoid_fast(gib[h] + ghb[h]);
  float z = sigmoid_fast(gib[512 + h] + ghb[512 + h]);
  float n = tanh_fast(gib[1024 + h] + r * ghb[1024 + h]);
  float h0 = hidden[idx];
  float hn = (1.f - z) * n + z * h0;
  outh[idx] = hn;
  hnewbf[idx] = f2bf(hn);
}

// ---------------------------------------------------------------------------
extern "C" void kernel_launch(void* const* d_in, const int* in_sizes, int n_in,
                              void* d_out, int out_size, void* d_ws,
                              size_t ws_size, hipStream_t stream) {
  const int* x = (const int*)d_in[0];
  const float* hidden = (const float*)d_in[1];   // (1,2048,512)
  const float* enc = (const float*)d_in[2];      // (2048,128,512)
  const float* embt = (const float*)d_in[3];     // (128,300)
  const float* W1w = (const float*)d_in[4];
  const float* W1b = (const float*)d_in[5];
  const float* W2w = (const float*)d_in[6];
  const float* W2b = (const float*)d_in[7];
  const float* Vw = (const float*)d_in[8];
  // d_in[9] = V_b: unused (softmax shift-invariant)
  const float* wih = (const float*)d_in[10];     // (1536,812)
  const float* whh = (const float*)d_in[11];     // (1536,512)
  const float* bih = (const float*)d_in[12];
  const float* bhh = (const float*)d_in[13];
  const float* fc1w = (const float*)d_in[14];    // (300,512)
  const float* fc1b = (const float*)d_in[15];
  const float* fc2w = (const float*)d_in[16];    // (128,300)
  const float* fc2b = (const float*)d_in[17];

  float* out_y = (float*)d_out;                  // (2048,128)
  float* out_h = out_y + 2048 * 128;             // (2048,512)

  char* ws = (char*)d_ws;
  size_t o = 0;
  auto alloc = [&](size_t bytes) {
    size_t r = o;
    o += (bytes + 255) & ~(size_t)255;
    return r;
  };
  unsigned short* W1bf = (unsigned short*)(ws + alloc(512 * 512 * 2));
  unsigned short* W2bf = (unsigned short*)(ws + alloc(512 * 512 * 2));
  unsigned short* wihbf = (unsigned short*)(ws + alloc(1536 * 832 * 2));
  unsigned short* whhbf = (unsigned short*)(ws + alloc(1536 * 512 * 2));
  unsigned short* fc1wbf = (unsigned short*)(ws + alloc(384 * 512 * 2));
  unsigned short* fc2wbf = (unsigned short*)(ws + alloc(128 * 384 * 2));
  unsigned short* hidbf = (unsigned short*)(ws + alloc(2048 * 512 * 2));
  unsigned short* ginbf = (unsigned short*)(ws + alloc((size_t)2048 * 832 * 2));
  float* keyb = (float*)(ws + alloc(512 * 4));
  float* fc1bp = (float*)(ws + alloc(384 * 4));
  float* key = (float*)(ws + alloc((size_t)2048 * 512 * 4));
  float* gi = (float*)(ws + alloc((size_t)2048 * 1536 * 4));
  float* gh = (float*)(ws + alloc((size_t)2048 * 1536 * 4));
  unsigned short* hnewbf = (unsigned short*)(ws + alloc(2048 * 512 * 2));
  unsigned short* a1bf = (unsigned short*)(ws + alloc((size_t)2048 * 384 * 2));

  // ---- prep: all bf16 conversions + biases + embedding in ONE launch ----
  prep_all<<<PREP_BLOCKS, 256, 0, stream>>>(
      W1w, W1bf, W2w, W2bf, wih, wihbf, whh, whhbf, fc1w, fc1wbf, fc2w, fc2wbf,
      hidden, hidbf, x, embt, ginbf, W1b, W2b, keyb, fc1b, fc1bp);

  // ---- key = h0 @ W2^T + (W2_b + W1_b) ----
  gemm_bt<0><<<dim3(16, 4), 256, 0, stream>>>(hidbf, 512, W2bf, 512, keyb,
                                              (void*)key, 512, 512);

  // ---- fused attention -> ctx into gin[:, 0:512] ----
  (void)hipFuncSetAttribute((const void*)attn_kernel,
                            hipFuncAttributeMaxDynamicSharedMemorySize,
                            ATTN_LDS_BYTES);
  attn_kernel<<<2048, 512, ATTN_LDS_BYTES, stream>>>(enc, W1bf, key, Vw, ginbf);

  // ---- GRU matmuls ----
  gemm_bt<0><<<dim3(16, 12), 256, 0, stream>>>(hidbf, 512, whhbf, 512, bhh,
                                               (void*)gh, 1536, 512);
  gemm_bt<0><<<dim3(16, 12), 256, 0, stream>>>(ginbf, 832, wihbf, 832, bih,
                                               (void*)gi, 1536, 832);
  gru_kernel<<<2048 * 512 / 256, 256, 0, stream>>>(gi, gh, hidden, out_h, hnewbf);

  // ---- head: a1 = lrelu(h_new@fc1^T+b) [bf16], y = a1@fc2^T+b -> d_out ----
  gemm_bt<1><<<dim3(16, 3), 256, 0, stream>>>(hnewbf, 512, fc1wbf, 512, fc1bp,
                                              (void*)a1bf, 384, 512);
  gemm_bt<0><<<dim3(16, 1), 256, 0, stream>>>(a1bf, 384, fc2wbf, 384, fc2b,
                                              (void*)out_y, 128, 384);
}